// Round 16
// baseline (56.400 us; speedup 1.0000x reference)
//
#include <hip/hip_runtime.h>
#include <math.h>

#define T_DIM 512
#define B_DIM 64
#define D_DIM 256
#define F_DIM 256
#define ALPHA 0.2f
#define L2E 1.44269504089f
#define NEGL -1.0e38f

// workspace layout (floats). Every slot consumed is written the same call.
#define U_OFF 0
#define V_OFF 256
#define Q_OFF 512
#define FC_OFF (Q_OFF + B_DIM * T_DIM)    // float2 fc[3][B][T] = (f1_i, ci_i)

__device__ __forceinline__ float dot4(float4 a, float4 b) {
    return a.x * b.x + a.y * b.y + a.z * b.z + a.w * b.w;
}

// Wave64 sum via DPP butterfly (VALU-rate, no LDS pipe). Result in lane 63.
__device__ __forceinline__ float dpp_sum(float x) {
    union { float f; int i; } a, t;
    a.f = x;
    t.i = __builtin_amdgcn_update_dpp(0, a.i, 0x111, 0xf, 0xf, true); a.f += t.f; // row_shr:1
    t.i = __builtin_amdgcn_update_dpp(0, a.i, 0x112, 0xf, 0xf, true); a.f += t.f; // row_shr:2
    t.i = __builtin_amdgcn_update_dpp(0, a.i, 0x114, 0xf, 0xf, true); a.f += t.f; // row_shr:4
    t.i = __builtin_amdgcn_update_dpp(0, a.i, 0x118, 0xf, 0xf, true); a.f += t.f; // row_shr:8
    t.i = __builtin_amdgcn_update_dpp(0, a.i, 0x142, 0xf, 0xf, true); a.f += t.f; // row_bcast:15
    t.i = __builtin_amdgcn_update_dpp(0, a.i, 0x143, 0xf, 0xf, true); a.f += t.f; // row_bcast:31
    return a.f;  // lane 63 holds the wave sum
}

// ---------- Node 1: u = W@a1, v = W@a2; zero d_out. 64 blocks x 256 thr ----------
__global__ __launch_bounds__(256) void g_uv(const float* __restrict__ W,
                                            const float* __restrict__ a1,
                                            const float* __restrict__ a2,
                                            float* __restrict__ ws,
                                            float* __restrict__ out) {
    int tid = threadIdx.x;
    out[blockIdx.x * 256 + tid] = 0.f;     // zero d_out for Node 3 atomics
    int wave = tid >> 6, lane = tid & 63;
    int d = blockIdx.x * 4 + wave;
    float4 wv = ((const float4*)(W + (size_t)d * F_DIM))[lane];
    float4 a1v = ((const float4*)a1)[lane];
    float4 a2v = ((const float4*)a2)[lane];
    float p = dpp_sum(dot4(wv, a1v));
    float q = dpp_sum(dot4(wv, a2v));
    if (lane == 63) {
        ws[U_OFF + d] = p;
        ws[V_OFF + d] = q;
    }
}

// ---------- Node 2: fused pq + row pass. 256 blocks (b, ic) x 1024 thr ----------
// q for all t (x4 redundant, 1 DPP chain), p only for this block's 130-row slice,
// then R13's proven row body (8 j-octants, 16 unrolled float4 iters) from LDS.
__global__ __launch_bounds__(1024) void g_rowpq(const float* __restrict__ x,
                                                const int* __restrict__ turns,
                                                float* __restrict__ ws) {
    int b = blockIdx.x >> 2, ic = blockIdx.x & 3;
    int tid = threadIdx.x, wave = tid >> 6, lane = tid & 63;
    int i0 = ic * 128;
    __shared__ float su[D_DIM], sv[D_DIM];
    __shared__ float sp[T_DIM], sq[T_DIM], f2L[T_DIM];
    __shared__ float part[8][128];
    __shared__ float redm[8];
    if (tid < 64) ((float4*)su)[tid] = ((const float4*)(ws + U_OFF))[tid];
    else if (tid < 128) ((float4*)sv)[tid - 64] = ((const float4*)(ws + V_OFF))[tid - 64];
    __syncthreads();
    int tn = turns[b];
    float4 uu = ((const float4*)su)[lane];
    float4 vv = ((const float4*)sv)[lane];

    // q for all t: wave handles t = wave + 16*(8c+k); clamp loads, DPP reduce
    {
        float4 xv[8];
#pragma unroll
        for (int c = 0; c < 4; ++c) {
#pragma unroll
            for (int k = 0; k < 8; ++k) {
                int t = min(wave + 16 * (c * 8 + k), tn);   // always valid address
                xv[k] = ((const float4*)x)[((size_t)t * B_DIM + b) * (D_DIM / 4) + lane];
            }
#pragma unroll
            for (int k = 0; k < 8; ++k) {
                int t = wave + 16 * (c * 8 + k);
                if (t <= tn) {                              // wave-uniform
                    float qq = dpp_sum(dot4(xv[k], vv));
                    if (lane == 63) {
                        sq[t] = qq;
                        if (t >= i0 && t < i0 + 128)        // each quarter written once
                            ws[Q_OFF + b * T_DIM + t] = qq;
                    }
                }
            }
        }
    }
    // p for t in [i0, i0+144): wave handles t = i0 + wave + 16*k, k=0..8
    {
        float4 xv[9];
#pragma unroll
        for (int k = 0; k < 9; ++k) {
            int t = min(min(i0 + wave + 16 * k, tn), T_DIM - 1);
            xv[k] = ((const float4*)x)[((size_t)t * B_DIM + b) * (D_DIM / 4) + lane];
        }
#pragma unroll
        for (int k = 0; k < 9; ++k) {
            int t = i0 + wave + 16 * k;
            if (t < T_DIM && t <= tn) {                     // wave-uniform
                float pp = dpp_sum(dot4(xv[k], uu));
                if (lane == 63) sp[t] = pp;
            }
        }
    }
    __syncthreads();

    // row pass per w (R13 g_row body, LDS-sourced)
    for (int w = 1; w <= 3; ++w) {
        int cnt = tn - w + 2;
        if (cnt > T_DIM) cnt = T_DIM;
        if (cnt <= 0) continue;            // block-uniform; fc never read for this w
        float scale = L2E / (float)w;
        if (tid < 512) {
            int j = tid;
            float v = NEGL;
            if (j < cnt) {                 // j+w-1 <= tn: sq valid
                float a = sq[j];
                if (w > 1) a += sq[j + 1];
                if (w > 2) a += sq[j + 2];
                v = a * scale;
            }
            f2L[j] = v;                    // padded NEGL beyond cnt
            float m = v;
            for (int off = 32; off > 0; off >>= 1) m = fmaxf(m, __shfl_down(m, off));
            if (lane == 0) redm[wave] = m;
        }
        __syncthreads();
        float M = redm[0];
#pragma unroll
        for (int k = 1; k < 8; ++k) M = fmaxf(M, redm[k]);

        int il = tid & 127, oct = tid >> 7;
        int i = i0 + il;
        float r = 0.f;
        if (i < cnt) {
            float a = sp[i];
            if (w > 1) a += sp[i + 1];
            if (w > 2) a += sp[i + 2];
            float f1 = a * scale;
            float s0 = f1 + M;
            float mrow = fmaxf(s0, ALPHA * s0);   // analytic row max (lrelu monotone)
            const float4* fv = (const float4*)(f2L + oct * 64);
#pragma unroll 4
            for (int k = 0; k < 16; ++k) {        // 64 j's per octant, pad-safe
                float4 f = fv[k];
                float sa = f1 + f.x, sb = f1 + f.y, sc = f1 + f.z, sd = f1 + f.w;
                sa = fmaxf(sa, ALPHA * sa); sb = fmaxf(sb, ALPHA * sb);
                sc = fmaxf(sc, ALPHA * sc); sd = fmaxf(sd, ALPHA * sd);
                r += __builtin_amdgcn_exp2f(sa - mrow) + __builtin_amdgcn_exp2f(sb - mrow)
                   + __builtin_amdgcn_exp2f(sc - mrow) + __builtin_amdgcn_exp2f(sd - mrow);
            }
        }
        part[oct][il] = r;
        __syncthreads();
        if (tid < 128) {
            int i2 = i0 + tid;
            float2 pr = make_float2(0.f, 3.0e38f);   // pad: exp2(s - 3e38) = 0
            if (i2 < cnt) {
                float rt = part[0][tid];
#pragma unroll
                for (int k = 1; k < 8; ++k) rt += part[k][tid];
                float a = sp[i2];
                if (w > 1) a += sp[i2 + 1];
                if (w > 2) a += sp[i2 + 2];
                float f1 = a * scale;
                float s0 = f1 + M;
                float mrow = fmaxf(s0, ALPHA * s0);
                pr = make_float2(f1, mrow + __builtin_amdgcn_logf(rt));   // log2 domain
            }
            ((float2*)(ws + FC_OFF))[((w - 1) * B_DIM + b) * T_DIM + i2] = pr;
        }
        __syncthreads();                   // f2L/part reused next w
    }
}

// ---------- Node 3: col pass + Z + GEMV -> atomicAdd out. 256 blocks x 512 ----------
// R13-proven body, unchanged.
__global__ __launch_bounds__(512) void g_colzout(const float* __restrict__ x,
                                                 const int* __restrict__ turns,
                                                 const float* __restrict__ W,
                                                 const float* __restrict__ ws,
                                                 float* __restrict__ out) {
    int b = blockIdx.x >> 2, chunk = blockIdx.x & 3;
    int tn = turns[b];
    int t0 = chunk * 128;
    if (t0 > tn) return;                   // C=0 there; out zeroed in Node 1
    int tid = threadIdx.x;
    __shared__ float sq[T_DIM];
    __shared__ float4 fcs4[3][T_DIM / 2];  // fc pairs, float4 = 2 (f1,ci) pairs
    __shared__ float Gs[3][132];
    __shared__ float partq[128][4];
    __shared__ float part2[2][128];
    __shared__ float Cs[128];
    __shared__ float4 zp[512];
    __shared__ float Zs[D_DIM];
    __shared__ float ored[512];

    if (tid < 128) ((float4*)sq)[tid] = ((const float4*)(ws + Q_OFF + b * T_DIM))[tid];
    for (int k = tid; k < 3 * 256; k += 512) {
        int wi = k >> 8, kk = k & 255;
        fcs4[wi][kk] = ((const float4*)(ws + FC_OFF))[(wi * B_DIM + b) * 256 + kk];
    }
    __syncthreads();

    for (int w = 1; w <= 3; ++w) {
        int cw = tn - w + 2;
        if (cw > T_DIM) cw = T_DIM;
        bool act = cw > 0;                 // block-uniform
        float scale = L2E / (float)w;
        if (act) {
            // phase I: j = t0 + (tid>>2), i-quarter iq = tid&3 (64 float4 = 128 i)
            {
                int jj = tid >> 2, iq = tid & 3;
                int j = t0 + jj;
                float acc = 0.f;
                if (j < cw) {
                    float a = sq[j];
                    if (w > 1) a += sq[j + 1];
                    if (w > 2) a += sq[j + 2];
                    float f2j = a * scale;
                    const float4* fv = fcs4[w - 1] + iq * 64;
                    for (int k = 0; k < 64; ++k) {       // pad-safe
                        float4 f = fv[k];
                        float sa = f.x + f2j, sb = f.z + f2j;
                        sa = fmaxf(sa, ALPHA * sa); sb = fmaxf(sb, ALPHA * sb);
                        acc += __builtin_amdgcn_exp2f(sa - f.y)
                             + __builtin_amdgcn_exp2f(sb - f.w);
                    }
                }
                partq[jj][iq] = acc;
            }
            // phase II: j = t0-2, t0-1; 128-way i-split (2 float4 = 4 i each)
            if (tid < 256) {
                int e = tid >> 7, q2 = tid & 127;
                int j2 = t0 - 2 + e;
                float acc = 0.f;
                if (j2 >= 0 && j2 < cw) {
                    float a = sq[j2];
                    if (w > 1) a += sq[j2 + 1];
                    if (w > 2) a += sq[j2 + 2];
                    float f2j = a * scale;
                    const float4* fv = fcs4[w - 1] + q2 * 2;
#pragma unroll
                    for (int k = 0; k < 2; ++k) {
                        float4 f = fv[k];
                        float sa = f.x + f2j, sb = f.z + f2j;
                        sa = fmaxf(sa, ALPHA * sa); sb = fmaxf(sb, ALPHA * sb);
                        acc += __builtin_amdgcn_exp2f(sa - f.y)
                             + __builtin_amdgcn_exp2f(sb - f.w);
                    }
                }
                part2[e][q2] = acc;
            }
        }
        __syncthreads();
        if (act) {
            float invc = 1.0f / (float)cw;
            if (tid < 128) {
                int j = t0 + tid;
                float s = partq[tid][0] + partq[tid][1] + partq[tid][2] + partq[tid][3];
                Gs[w - 1][2 + tid] = (j < cw) ? s * invc : 0.f;
            } else if (tid < 130) {
                int e = tid - 128;
                int j2 = t0 - 2 + e;
                float s = 0.f;
                for (int k = 0; k < 128; ++k) s += part2[e][k];
                Gs[w - 1][e] = (j2 >= 0 && j2 < cw) ? s * invc : 0.f;
            }
        } else if (tid < 132) {
            Gs[w - 1][tid] = 0.f;
        }
        __syncthreads();
    }

    // C[t] with vws folded
    if (tid < 128) {
        float g1 = Gs[0][2 + tid];
        float g2 = Gs[1][2 + tid] + Gs[1][1 + tid];
        float g3 = Gs[2][2 + tid] + Gs[2][1 + tid] + Gs[2][tid];
        float vws = 1.f + (tn >= 1 ? 1.f : 0.f) + (tn >= 2 ? 1.f : 0.f);
        Cs[tid] = (g1 + 0.5f * g2 + (1.0f / 3.0f) * g3) / vws;
    }
    __syncthreads();

    // Z accumulate over this t-chunk (proven body)
    int wave = tid >> 6, lane = tid & 63;
    float4 z = make_float4(0.f, 0.f, 0.f, 0.f);
    {
        size_t base = ((size_t)(t0 + wave * 16) * B_DIM + b) * (D_DIM / 4) + lane;
#pragma unroll 8
        for (int tt = 0; tt < 16; ++tt) {
            float c = Cs[wave * 16 + tt];
            float4 xv = ((const float4*)x)[base + (size_t)tt * (B_DIM * D_DIM / 4)];
            z.x += c * xv.x; z.y += c * xv.y; z.z += c * xv.z; z.w += c * xv.w;
        }
    }
    zp[tid] = z;
    __syncthreads();
    if (tid < 64) {
        float4 a = zp[tid];
#pragma unroll
        for (int k = 1; k < 8; ++k) {
            float4 bb = zp[k * 64 + tid];
            a.x += bb.x; a.y += bb.y; a.z += bb.z; a.w += bb.w;
        }
        ((float4*)Zs)[tid] = a;
    }
    __syncthreads();
    int f = tid & 255, dh = tid >> 8;
    float acc = 0.f;
#pragma unroll 8
    for (int dd = dh * 128; dd < dh * 128 + 128; ++dd)
        acc += Zs[dd] * W[(size_t)dd * F_DIM + f];
    ored[tid] = acc;
    __syncthreads();
    if (tid < 256)
        atomicAdd(&out[b * F_DIM + tid], ored[tid] + ored[tid + 256]);
}

extern "C" void kernel_launch(void* const* d_in, const int* in_sizes, int n_in,
                              void* d_out, int out_size, void* d_ws, size_t ws_size,
                              hipStream_t stream) {
    const float* x = (const float*)d_in[0];     // (T,B,D) fp32
    const int* turns = (const int*)d_in[1];     // (B,) int32
    const float* W = (const float*)d_in[2];     // (D,F)
    const float* a1 = (const float*)d_in[3];    // (F,)
    const float* a2 = (const float*)d_in[4];    // (F,)
    float* out = (float*)d_out;                 // (B,F)
    float* ws = (float*)d_ws;

    g_uv<<<B_DIM, 256, 0, stream>>>(W, a1, a2, ws, out);
    g_rowpq<<<256, 1024, 0, stream>>>(x, turns, ws);
    g_colzout<<<B_DIM * 4, 512, 0, stream>>>(x, turns, W, ws, out);
}

// Round 17
// 47.181 us; speedup vs baseline: 1.1954x; 1.1954x over previous
//
#include <hip/hip_runtime.h>
#include <math.h>

#define T_DIM 512
#define B_DIM 64
#define D_DIM 256
#define F_DIM 256
#define ALPHA 0.2f
#define L2E 1.44269504089f
#define NEGL -1.0e38f

// workspace layout (floats). Every slot consumed is written the same call.
#define U_OFF 0
#define V_OFF 256
#define P_OFF 512
#define Q_OFF (P_OFF + B_DIM * T_DIM)
#define FC_OFF (Q_OFF + B_DIM * T_DIM)    // float2 fc[3][B][T] = (f1_i, ci_i)

__device__ __forceinline__ float dot4(float4 a, float4 b) {
    return a.x * b.x + a.y * b.y + a.z * b.z + a.w * b.w;
}

// Wave64 sum via DPP butterfly (VALU-rate, no LDS pipe). Result in lane 63.
__device__ __forceinline__ float dpp_sum(float x) {
    union { float f; int i; } a, t;
    a.f = x;
    t.i = __builtin_amdgcn_update_dpp(0, a.i, 0x111, 0xf, 0xf, true); a.f += t.f; // row_shr:1
    t.i = __builtin_amdgcn_update_dpp(0, a.i, 0x112, 0xf, 0xf, true); a.f += t.f; // row_shr:2
    t.i = __builtin_amdgcn_update_dpp(0, a.i, 0x114, 0xf, 0xf, true); a.f += t.f; // row_shr:4
    t.i = __builtin_amdgcn_update_dpp(0, a.i, 0x118, 0xf, 0xf, true); a.f += t.f; // row_shr:8
    t.i = __builtin_amdgcn_update_dpp(0, a.i, 0x142, 0xf, 0xf, true); a.f += t.f; // row_bcast:15
    t.i = __builtin_amdgcn_update_dpp(0, a.i, 0x143, 0xf, 0xf, true); a.f += t.f; // row_bcast:31
    return a.f;  // lane 63 holds the wave sum
}

// ---------- Node 1: u = W@a1, v = W@a2; zero d_out. 64 blocks x 256 thr ----------
__global__ __launch_bounds__(256) void g_uv(const float* __restrict__ W,
                                            const float* __restrict__ a1,
                                            const float* __restrict__ a2,
                                            float* __restrict__ ws,
                                            float* __restrict__ out) {
    int tid = threadIdx.x;
    out[blockIdx.x * 256 + tid] = 0.f;     // zero d_out for Node 4 atomics
    int wave = tid >> 6, lane = tid & 63;
    int d = blockIdx.x * 4 + wave;
    float4 wv = ((const float4*)(W + (size_t)d * F_DIM))[lane];
    float4 a1v = ((const float4*)a1)[lane];
    float4 a2v = ((const float4*)a2)[lane];
    float p = dpp_sum(dot4(wv, a1v));
    float q = dpp_sum(dot4(wv, a2v));
    if (lane == 63) {
        ws[U_OFF + d] = p;
        ws[V_OFF + d] = q;
    }
}

// ---------- Node 2: p,q dot products. 512 blocks x 512 thr ----------
// Clamp-trick unconditional loads (8 in flight) + DPP reduction.
__global__ __launch_bounds__(512) void g_pq(const float* __restrict__ x,
                                            const int* __restrict__ turns,
                                            float* __restrict__ ws) {
    __shared__ float su[D_DIM], sv[D_DIM];
    int tid = threadIdx.x;
    if (tid < 64) ((float4*)su)[tid] = ((const float4*)(ws + U_OFF))[tid];
    else if (tid < 128) ((float4*)sv)[tid - 64] = ((const float4*)(ws + V_OFF))[tid - 64];
    __syncthreads();
    int lane = tid & 63;
    int gw = blockIdx.x * 8 + (tid >> 6);  // [0, 4096)
    int b = gw & 63;
    int tbase = gw >> 6;                   // [0, 64)
    int tn = turns[b];
    float4 uv = ((const float4*)su)[lane];
    float4 vv = ((const float4*)sv)[lane];
    float4 xv[8];
#pragma unroll
    for (int k = 0; k < 8; ++k) {
        int t = min(tbase + k * 64, tn);   // always valid address
        xv[k] = ((const float4*)x)[((size_t)t * B_DIM + b) * (D_DIM / 4) + lane];
    }
#pragma unroll
    for (int k = 0; k < 8; ++k) {
        int t = tbase + k * 64;
        if (t <= tn) {                     // wave-uniform
            float pp = dpp_sum(dot4(xv[k], uv));
            float qq = dpp_sum(dot4(xv[k], vv));
            if (lane == 63) {
                ws[P_OFF + b * T_DIM + t] = pp;
                ws[Q_OFF + b * T_DIM + t] = qq;
            }
        }
    }
}

// ---------- Node 3: balanced row pass, no atomics. 768 blocks (b,w,ic) x 1024 ----------
// Each block: full-j row sums for its 128 i's -> fc[(w-1)][b][i] = (f1_i, ci_i).
// Pads (i >= cnt) written as (0, 3e38) so downstream float4 loops need no tails.
__global__ __launch_bounds__(1024) void g_row(const int* __restrict__ turns,
                                              float* __restrict__ ws) {
    int bi = blockIdx.x, tid = threadIdx.x;
    int b = bi / 12, rem = bi % 12;
    int w = (rem >> 2) + 1, ic = rem & 3;
    int tn = turns[b];
    int cnt = tn - w + 2;
    if (cnt > T_DIM) cnt = T_DIM;
    float2* FC = (float2*)(ws + FC_OFF) + ((w - 1) * B_DIM + b) * T_DIM;
    if (cnt <= 0) return;                  // block-uniform; fc never read for this w
    __shared__ float sp[T_DIM], sq[T_DIM], f2L[T_DIM];
    __shared__ float part[8][128];
    __shared__ float redm[8];
    if (tid < 128) ((float4*)sp)[tid] = ((const float4*)(ws + P_OFF + b * T_DIM))[tid];
    else if (tid < 256) ((float4*)sq)[tid - 128] = ((const float4*)(ws + Q_OFF + b * T_DIM))[tid - 128];
    __syncthreads();
    float scale = L2E / (float)w;
    int wave = tid >> 6, lane = tid & 63;
    if (tid < 512) {
        int j = tid;
        float v = NEGL;
        if (j < cnt) {                     // j+w-1 <= tn: valid
            float a = sq[j];
            if (w > 1) a += sq[j + 1];
            if (w > 2) a += sq[j + 2];
            v = a * scale;
        }
        f2L[j] = v;                        // padded NEGL beyond cnt
        float m = v;
        for (int off = 32; off > 0; off >>= 1) m = fmaxf(m, __shfl_down(m, off));
        if (lane == 0) redm[wave] = m;
    }
    __syncthreads();
    float M = redm[0];
#pragma unroll
    for (int k = 1; k < 8; ++k) M = fmaxf(M, redm[k]);

    int il = tid & 127, oct = tid >> 7;
    int i = ic * 128 + il;
    float r = 0.f;
    if (i < cnt) {
        float a = sp[i];
        if (w > 1) a += sp[i + 1];
        if (w > 2) a += sp[i + 2];
        float f1 = a * scale;
        float s0 = f1 + M;
        float mrow = fmaxf(s0, ALPHA * s0);   // analytic row max (lrelu monotone)
        const float4* fv = (const float4*)(f2L + oct * 64);
#pragma unroll 4
        for (int k = 0; k < 16; ++k) {        // 64 j's per octant, pad-safe
            float4 f = fv[k];
            float sa = f1 + f.x, sb = f1 + f.y, sc = f1 + f.z, sd = f1 + f.w;
            sa = fmaxf(sa, ALPHA * sa); sb = fmaxf(sb, ALPHA * sb);
            sc = fmaxf(sc, ALPHA * sc); sd = fmaxf(sd, ALPHA * sd);
            r += __builtin_amdgcn_exp2f(sa - mrow) + __builtin_amdgcn_exp2f(sb - mrow)
               + __builtin_amdgcn_exp2f(sc - mrow) + __builtin_amdgcn_exp2f(sd - mrow);
        }
    }
    part[oct][il] = r;
    __syncthreads();
    if (tid < 128) {
        int i2 = ic * 128 + tid;
        float2 pr = make_float2(0.f, 3.0e38f);   // pad: exp2(s - 3e38) = 0
        if (i2 < cnt) {
            float rt = part[0][tid];
#pragma unroll
            for (int k = 1; k < 8; ++k) rt += part[k][tid];
            float a = sp[i2];
            if (w > 1) a += sp[i2 + 1];
            if (w > 2) a += sp[i2 + 2];
            float f1 = a * scale;
            float s0 = f1 + M;
            float mrow = fmaxf(s0, ALPHA * s0);
            pr = make_float2(f1, mrow + __builtin_amdgcn_logf(rt));   // log2 domain
        }
        FC[i2] = pr;
    }
}

// ---------- Node 4: col pass + Z + GEMV -> atomicAdd out. 256 blocks x 512 ----------
__global__ __launch_bounds__(512) void g_colzout(const float* __restrict__ x,
                                                 const int* __restrict__ turns,
                                                 const float* __restrict__ W,
                                                 const float* __restrict__ ws,
                                                 float* __restrict__ out) {
    int b = blockIdx.x >> 2, chunk = blockIdx.x & 3;
    int tn = turns[b];
    int t0 = chunk * 128;
    if (t0 > tn) return;                   // C=0 there; out zeroed in Node 1
    int tid = threadIdx.x;
    __shared__ float sq[T_DIM];
    __shared__ float4 fcs4[3][T_DIM / 2];  // fc pairs, float4 = 2 (f1,ci) pairs
    __shared__ float Gs[3][132];
    __shared__ float partq[128][4];
    __shared__ float part2[2][128];
    __shared__ float Cs[128];
    __shared__ float4 zp[512];
    __shared__ float Zs[D_DIM];
    __shared__ float ored[512];

    if (tid < 128) ((float4*)sq)[tid] = ((const float4*)(ws + Q_OFF + b * T_DIM))[tid];
    for (int k = tid; k < 3 * 256; k += 512) {
        int wi = k >> 8, kk = k & 255;
        fcs4[wi][kk] = ((const float4*)(ws + FC_OFF))[(wi * B_DIM + b) * 256 + kk];
    }
    __syncthreads();

    for (int w = 1; w <= 3; ++w) {
        int cw = tn - w + 2;
        if (cw > T_DIM) cw = T_DIM;
        bool act = cw > 0;                 // block-uniform
        float scale = L2E / (float)w;
        if (act) {
            // phase I: j = t0 + (tid>>2), i-quarter iq = tid&3 (64 float4 = 128 i)
            {
                int jj = tid >> 2, iq = tid & 3;
                int j = t0 + jj;
                float acc = 0.f;
                if (j < cw) {
                    float a = sq[j];
                    if (w > 1) a += sq[j + 1];
                    if (w > 2) a += sq[j + 2];
                    float f2j = a * scale;
                    const float4* fv = fcs4[w - 1] + iq * 64;
                    for (int k = 0; k < 64; ++k) {       // pad-safe
                        float4 f = fv[k];
                        float sa = f.x + f2j, sb = f.z + f2j;
                        sa = fmaxf(sa, ALPHA * sa); sb = fmaxf(sb, ALPHA * sb);
                        acc += __builtin_amdgcn_exp2f(sa - f.y)
                             + __builtin_amdgcn_exp2f(sb - f.w);
                    }
                }
                partq[jj][iq] = acc;
            }
            // phase II: j = t0-2, t0-1; 128-way i-split (2 float4 = 4 i each)
            if (tid < 256) {
                int e = tid >> 7, q2 = tid & 127;
                int j2 = t0 - 2 + e;
                float acc = 0.f;
                if (j2 >= 0 && j2 < cw) {
                    float a = sq[j2];
                    if (w > 1) a += sq[j2 + 1];
                    if (w > 2) a += sq[j2 + 2];
                    float f2j = a * scale;
                    const float4* fv = fcs4[w - 1] + q2 * 2;
#pragma unroll
                    for (int k = 0; k < 2; ++k) {
                        float4 f = fv[k];
                        float sa = f.x + f2j, sb = f.z + f2j;
                        sa = fmaxf(sa, ALPHA * sa); sb = fmaxf(sb, ALPHA * sb);
                        acc += __builtin_amdgcn_exp2f(sa - f.y)
                             + __builtin_amdgcn_exp2f(sb - f.w);
                    }
                }
                part2[e][q2] = acc;
            }
        }
        __syncthreads();
        if (act) {
            float invc = 1.0f / (float)cw;
            if (tid < 128) {
                int j = t0 + tid;
                float s = partq[tid][0] + partq[tid][1] + partq[tid][2] + partq[tid][3];
                Gs[w - 1][2 + tid] = (j < cw) ? s * invc : 0.f;
            } else if (tid < 130) {
                int e = tid - 128;
                int j2 = t0 - 2 + e;
                float s = 0.f;
                for (int k = 0; k < 128; ++k) s += part2[e][k];
                Gs[w - 1][e] = (j2 >= 0 && j2 < cw) ? s * invc : 0.f;
            }
        } else if (tid < 132) {
            Gs[w - 1][tid] = 0.f;
        }
        __syncthreads();
    }

    // C[t] with vws folded
    if (tid < 128) {
        float g1 = Gs[0][2 + tid];
        float g2 = Gs[1][2 + tid] + Gs[1][1 + tid];
        float g3 = Gs[2][2 + tid] + Gs[2][1 + tid] + Gs[2][tid];
        float vws = 1.f + (tn >= 1 ? 1.f : 0.f) + (tn >= 2 ? 1.f : 0.f);
        Cs[tid] = (g1 + 0.5f * g2 + (1.0f / 3.0f) * g3) / vws;
    }
    __syncthreads();

    // Z accumulate over this t-chunk (proven body)
    int wave = tid >> 6, lane = tid & 63;
    float4 z = make_float4(0.f, 0.f, 0.f, 0.f);
    {
        size_t base = ((size_t)(t0 + wave * 16) * B_DIM + b) * (D_DIM / 4) + lane;
#pragma unroll 8
        for (int tt = 0; tt < 16; ++tt) {
            float c = Cs[wave * 16 + tt];
            float4 xv = ((const float4*)x)[base + (size_t)tt * (B_DIM * D_DIM / 4)];
            z.x += c * xv.x; z.y += c * xv.y; z.z += c * xv.z; z.w += c * xv.w;
        }
    }
    zp[tid] = z;
    __syncthreads();
    if (tid < 64) {
        float4 a = zp[tid];
#pragma unroll
        for (int k = 1; k < 8; ++k) {
            float4 bb = zp[k * 64 + tid];
            a.x += bb.x; a.y += bb.y; a.z += bb.z; a.w += bb.w;
        }
        ((float4*)Zs)[tid] = a;
    }
    __syncthreads();
    int f = tid & 255, dh = tid >> 8;
    float acc = 0.f;
#pragma unroll 8
    for (int dd = dh * 128; dd < dh * 128 + 128; ++dd)
        acc += Zs[dd] * W[(size_t)dd * F_DIM + f];
    ored[tid] = acc;
    __syncthreads();
    if (tid < 256)
        atomicAdd(&out[b * F_DIM + tid], ored[tid] + ored[tid + 256]);
}

extern "C" void kernel_launch(void* const* d_in, const int* in_sizes, int n_in,
                              void* d_out, int out_size, void* d_ws, size_t ws_size,
                              hipStream_t stream) {
    const float* x = (const float*)d_in[0];     // (T,B,D) fp32
    const int* turns = (const int*)d_in[1];     // (B,) int32
    const float* W = (const float*)d_in[2];     // (D,F)
    const float* a1 = (const float*)d_in[3];    // (F,)
    const float* a2 = (const float*)d_in[4];    // (F,)
    float* out = (float*)d_out;                 // (B,F)
    float* ws = (float*)d_ws;

    g_uv<<<B_DIM, 256, 0, stream>>>(W, a1, a2, ws, out);
    g_pq<<<512, 512, 0, stream>>>(x, turns, ws);
    g_row<<<B_DIM * 12, 1024, 0, stream>>>(turns, ws);
    g_colzout<<<B_DIM * 4, 512, 0, stream>>>(x, turns, W, ws, out);
}

// Round 18
// 46.146 us; speedup vs baseline: 1.2222x; 1.0224x over previous
//
#include <hip/hip_runtime.h>
#include <math.h>

#define T_DIM 512
#define B_DIM 64
#define D_DIM 256
#define F_DIM 256
#define ALPHA 0.2f
#define L2E 1.44269504089f
#define NEGL -1.0e38f

// workspace layout (floats). Every slot consumed is written the same call.
#define U_OFF 0
#define V_OFF 256
#define P_OFF 512
#define Q_OFF (P_OFF + B_DIM * T_DIM)
#define FC_OFF (Q_OFF + B_DIM * T_DIM)    // float2 fc[3][B][T] = (f1_i, ci_i)

__device__ __forceinline__ float dot4(float4 a, float4 b) {
    return a.x * b.x + a.y * b.y + a.z * b.z + a.w * b.w;
}

// Wave64 sum via DPP butterfly (VALU-rate, no LDS pipe). Result in lane 63.
__device__ __forceinline__ float dpp_sum(float x) {
    union { float f; int i; } a, t;
    a.f = x;
    t.i = __builtin_amdgcn_update_dpp(0, a.i, 0x111, 0xf, 0xf, true); a.f += t.f; // row_shr:1
    t.i = __builtin_amdgcn_update_dpp(0, a.i, 0x112, 0xf, 0xf, true); a.f += t.f; // row_shr:2
    t.i = __builtin_amdgcn_update_dpp(0, a.i, 0x114, 0xf, 0xf, true); a.f += t.f; // row_shr:4
    t.i = __builtin_amdgcn_update_dpp(0, a.i, 0x118, 0xf, 0xf, true); a.f += t.f; // row_shr:8
    t.i = __builtin_amdgcn_update_dpp(0, a.i, 0x142, 0xf, 0xf, true); a.f += t.f; // row_bcast:15
    t.i = __builtin_amdgcn_update_dpp(0, a.i, 0x143, 0xf, 0xf, true); a.f += t.f; // row_bcast:31
    return a.f;  // lane 63 holds the wave sum
}

// ---------- Node 1: u = W@a1, v = W@a2; zero d_out. 64 blocks x 256 thr ----------
__global__ __launch_bounds__(256) void g_uv(const float* __restrict__ W,
                                            const float* __restrict__ a1,
                                            const float* __restrict__ a2,
                                            float* __restrict__ ws,
                                            float* __restrict__ out) {
    int tid = threadIdx.x;
    out[blockIdx.x * 256 + tid] = 0.f;     // zero d_out for Node 4 atomics
    int wave = tid >> 6, lane = tid & 63;
    int d = blockIdx.x * 4 + wave;
    float4 wv = ((const float4*)(W + (size_t)d * F_DIM))[lane];
    float4 a1v = ((const float4*)a1)[lane];
    float4 a2v = ((const float4*)a2)[lane];
    float p = dpp_sum(dot4(wv, a1v));
    float q = dpp_sum(dot4(wv, a2v));
    if (lane == 63) {
        ws[U_OFF + d] = p;
        ws[V_OFF + d] = q;
    }
}

// ---------- Node 2: p,q dot products. 512 blocks x 512 thr ----------
// Clamp-trick unconditional loads (8 in flight) + DPP reduction.
__global__ __launch_bounds__(512) void g_pq(const float* __restrict__ x,
                                            const int* __restrict__ turns,
                                            float* __restrict__ ws) {
    __shared__ float su[D_DIM], sv[D_DIM];
    int tid = threadIdx.x;
    if (tid < 64) ((float4*)su)[tid] = ((const float4*)(ws + U_OFF))[tid];
    else if (tid < 128) ((float4*)sv)[tid - 64] = ((const float4*)(ws + V_OFF))[tid - 64];
    __syncthreads();
    int lane = tid & 63;
    int gw = blockIdx.x * 8 + (tid >> 6);  // [0, 4096)
    int b = gw & 63;
    int tbase = gw >> 6;                   // [0, 64)
    int tn = turns[b];
    float4 uv = ((const float4*)su)[lane];
    float4 vv = ((const float4*)sv)[lane];
    float4 xv[8];
#pragma unroll
    for (int k = 0; k < 8; ++k) {
        int t = min(tbase + k * 64, tn);   // always valid address
        xv[k] = ((const float4*)x)[((size_t)t * B_DIM + b) * (D_DIM / 4) + lane];
    }
#pragma unroll
    for (int k = 0; k < 8; ++k) {
        int t = tbase + k * 64;
        if (t <= tn) {                     // wave-uniform
            float pp = dpp_sum(dot4(xv[k], uv));
            float qq = dpp_sum(dot4(xv[k], vv));
            if (lane == 63) {
                ws[P_OFF + b * T_DIM + t] = pp;
                ws[Q_OFF + b * T_DIM + t] = qq;
            }
        }
    }
}

// ---------- Node 3: balanced row pass, no atomics. 768 blocks (b,w,ic) x 1024 ----------
// Each block: full-j row sums for its 128 i's -> fc[(w-1)][b][i] = (f1_i, ci_i).
// Pads (i >= cnt) written as (0, 3e38) so downstream float4 loops need no tails.
// Octant guard (oct*64 < cnt) skips all-zero j-chunks wave-uniformly.
__global__ __launch_bounds__(1024) void g_row(const int* __restrict__ turns,
                                              float* __restrict__ ws) {
    int bi = blockIdx.x, tid = threadIdx.x;
    int b = bi / 12, rem = bi % 12;
    int w = (rem >> 2) + 1, ic = rem & 3;
    int tn = turns[b];
    int cnt = tn - w + 2;
    if (cnt > T_DIM) cnt = T_DIM;
    float2* FC = (float2*)(ws + FC_OFF) + ((w - 1) * B_DIM + b) * T_DIM;
    if (cnt <= 0) return;                  // block-uniform; fc never read for this w
    __shared__ float sp[T_DIM], sq[T_DIM], f2L[T_DIM];
    __shared__ float part[8][128];
    __shared__ float redm[8];
    if (tid < 128) ((float4*)sp)[tid] = ((const float4*)(ws + P_OFF + b * T_DIM))[tid];
    else if (tid < 256) ((float4*)sq)[tid - 128] = ((const float4*)(ws + Q_OFF + b * T_DIM))[tid - 128];
    __syncthreads();
    float scale = L2E / (float)w;
    int wave = tid >> 6, lane = tid & 63;
    if (tid < 512) {
        int j = tid;
        float v = NEGL;
        if (j < cnt) {                     // j+w-1 <= tn: valid
            float a = sq[j];
            if (w > 1) a += sq[j + 1];
            if (w > 2) a += sq[j + 2];
            v = a * scale;
        }
        f2L[j] = v;                        // padded NEGL beyond cnt
        float m = v;
        for (int off = 32; off > 0; off >>= 1) m = fmaxf(m, __shfl_down(m, off));
        if (lane == 0) redm[wave] = m;
    }
    __syncthreads();
    float M = redm[0];
#pragma unroll
    for (int k = 1; k < 8; ++k) M = fmaxf(M, redm[k]);

    int il = tid & 127, oct = tid >> 7;
    int i = ic * 128 + il;
    float r = 0.f;
    // oct*64 >= cnt -> whole j-chunk is NEGL-padded -> contribution exactly 0.
    // Guard is uniform over the octant's 2 waves; loop body/bounds unchanged.
    if (i < cnt && oct * 64 < cnt) {
        float a = sp[i];
        if (w > 1) a += sp[i + 1];
        if (w > 2) a += sp[i + 2];
        float f1 = a * scale;
        float s0 = f1 + M;
        float mrow = fmaxf(s0, ALPHA * s0);   // analytic row max (lrelu monotone)
        const float4* fv = (const float4*)(f2L + oct * 64);
#pragma unroll 4
        for (int k = 0; k < 16; ++k) {        // 64 j's per octant, pad-safe
            float4 f = fv[k];
            float sa = f1 + f.x, sb = f1 + f.y, sc = f1 + f.z, sd = f1 + f.w;
            sa = fmaxf(sa, ALPHA * sa); sb = fmaxf(sb, ALPHA * sb);
            sc = fmaxf(sc, ALPHA * sc); sd = fmaxf(sd, ALPHA * sd);
            r += __builtin_amdgcn_exp2f(sa - mrow) + __builtin_amdgcn_exp2f(sb - mrow)
               + __builtin_amdgcn_exp2f(sc - mrow) + __builtin_amdgcn_exp2f(sd - mrow);
        }
    }
    part[oct][il] = r;
    __syncthreads();
    if (tid < 128) {
        int i2 = ic * 128 + tid;
        float2 pr = make_float2(0.f, 3.0e38f);   // pad: exp2(s - 3e38) = 0
        if (i2 < cnt) {
            float rt = part[0][tid];
#pragma unroll
            for (int k = 1; k < 8; ++k) rt += part[k][tid];
            float a = sp[i2];
            if (w > 1) a += sp[i2 + 1];
            if (w > 2) a += sp[i2 + 2];
            float f1 = a * scale;
            float s0 = f1 + M;
            float mrow = fmaxf(s0, ALPHA * s0);
            pr = make_float2(f1, mrow + __builtin_amdgcn_logf(rt));   // log2 domain
        }
        FC[i2] = pr;
    }
}

// ---------- Node 4: col pass + Z + GEMV -> atomicAdd out. 256 blocks x 512 ----------
// Phase I re-indexed so the i-quarter is wave-uniform (iq = tid>>7) and skippable.
__global__ __launch_bounds__(512) void g_colzout(const float* __restrict__ x,
                                                 const int* __restrict__ turns,
                                                 const float* __restrict__ W,
                                                 const float* __restrict__ ws,
                                                 float* __restrict__ out) {
    int b = blockIdx.x >> 2, chunk = blockIdx.x & 3;
    int tn = turns[b];
    int t0 = chunk * 128;
    if (t0 > tn) return;                   // C=0 there; out zeroed in Node 1
    int tid = threadIdx.x;
    __shared__ float sq[T_DIM];
    __shared__ float4 fcs4[3][T_DIM / 2];  // fc pairs, float4 = 2 (f1,ci) pairs
    __shared__ float Gs[3][132];
    __shared__ float partq[128][4];
    __shared__ float part2[2][128];
    __shared__ float Cs[128];
    __shared__ float4 zp[512];
    __shared__ float Zs[D_DIM];
    __shared__ float ored[512];

    if (tid < 128) ((float4*)sq)[tid] = ((const float4*)(ws + Q_OFF + b * T_DIM))[tid];
    for (int k = tid; k < 3 * 256; k += 512) {
        int wi = k >> 8, kk = k & 255;
        fcs4[wi][kk] = ((const float4*)(ws + FC_OFF))[(wi * B_DIM + b) * 256 + kk];
    }
    __syncthreads();

    for (int w = 1; w <= 3; ++w) {
        int cw = tn - w + 2;
        if (cw > T_DIM) cw = T_DIM;
        bool act = cw > 0;                 // block-uniform
        float scale = L2E / (float)w;
        if (act) {
            // phase I: j = t0 + (tid&127), i-quarter iq = tid>>7 (wave-uniform).
            // iq*128 >= cw -> quarter is all pads -> contribution exactly 0.
            {
                int jj = tid & 127, iq = tid >> 7;
                int j = t0 + jj;
                float acc = 0.f;
                if (j < cw && iq * 128 < cw) {
                    float a = sq[j];
                    if (w > 1) a += sq[j + 1];
                    if (w > 2) a += sq[j + 2];
                    float f2j = a * scale;
                    const float4* fv = fcs4[w - 1] + iq * 64;
                    for (int k = 0; k < 64; ++k) {       // pad-safe
                        float4 f = fv[k];
                        float sa = f.x + f2j, sb = f.z + f2j;
                        sa = fmaxf(sa, ALPHA * sa); sb = fmaxf(sb, ALPHA * sb);
                        acc += __builtin_amdgcn_exp2f(sa - f.y)
                             + __builtin_amdgcn_exp2f(sb - f.w);
                    }
                }
                partq[jj][iq] = acc;
            }
            // phase II: j = t0-2, t0-1; 128-way i-split (2 float4 = 4 i each)
            if (tid < 256) {
                int e = tid >> 7, q2 = tid & 127;
                int j2 = t0 - 2 + e;
                float acc = 0.f;
                if (j2 >= 0 && j2 < cw) {
                    float a = sq[j2];
                    if (w > 1) a += sq[j2 + 1];
                    if (w > 2) a += sq[j2 + 2];
                    float f2j = a * scale;
                    const float4* fv = fcs4[w - 1] + q2 * 2;
#pragma unroll
                    for (int k = 0; k < 2; ++k) {
                        float4 f = fv[k];
                        float sa = f.x + f2j, sb = f.z + f2j;
                        sa = fmaxf(sa, ALPHA * sa); sb = fmaxf(sb, ALPHA * sb);
                        acc += __builtin_amdgcn_exp2f(sa - f.y)
                             + __builtin_amdgcn_exp2f(sb - f.w);
                    }
                }
                part2[e][q2] = acc;
            }
        }
        __syncthreads();
        if (act) {
            float invc = 1.0f / (float)cw;
            if (tid < 128) {
                int j = t0 + tid;
                float s = partq[tid][0] + partq[tid][1] + partq[tid][2] + partq[tid][3];
                Gs[w - 1][2 + tid] = (j < cw) ? s * invc : 0.f;
            } else if (tid < 130) {
                int e = tid - 128;
                int j2 = t0 - 2 + e;
                float s = 0.f;
                for (int k = 0; k < 128; ++k) s += part2[e][k];
                Gs[w - 1][e] = (j2 >= 0 && j2 < cw) ? s * invc : 0.f;
            }
        } else if (tid < 132) {
            Gs[w - 1][tid] = 0.f;
        }
        __syncthreads();
    }

    // C[t] with vws folded
    if (tid < 128) {
        float g1 = Gs[0][2 + tid];
        float g2 = Gs[1][2 + tid] + Gs[1][1 + tid];
        float g3 = Gs[2][2 + tid] + Gs[2][1 + tid] + Gs[2][tid];
        float vws = 1.f + (tn >= 1 ? 1.f : 0.f) + (tn >= 2 ? 1.f : 0.f);
        Cs[tid] = (g1 + 0.5f * g2 + (1.0f / 3.0f) * g3) / vws;
    }
    __syncthreads();

    // Z accumulate over this t-chunk (proven body)
    int wave = tid >> 6, lane = tid & 63;
    float4 z = make_float4(0.f, 0.f, 0.f, 0.f);
    {
        size_t base = ((size_t)(t0 + wave * 16) * B_DIM + b) * (D_DIM / 4) + lane;
#pragma unroll 8
        for (int tt = 0; tt < 16; ++tt) {
            float c = Cs[wave * 16 + tt];
            float4 xv = ((const float4*)x)[base + (size_t)tt * (B_DIM * D_DIM / 4)];
            z.x += c * xv.x; z.y += c * xv.y; z.z += c * xv.z; z.w += c * xv.w;
        }
    }
    zp[tid] = z;
    __syncthreads();
    if (tid < 64) {
        float4 a = zp[tid];
#pragma unroll
        for (int k = 1; k < 8; ++k) {
            float4 bb = zp[k * 64 + tid];
            a.x += bb.x; a.y += bb.y; a.z += bb.z; a.w += bb.w;
        }
        ((float4*)Zs)[tid] = a;
    }
    __syncthreads();
    int f = tid & 255, dh = tid >> 8;
    float acc = 0.f;
#pragma unroll 8
    for (int dd = dh * 128; dd < dh * 128 + 128; ++dd)
        acc += Zs[dd] * W[(size_t)dd * F_DIM + f];
    ored[tid] = acc;
    __syncthreads();
    if (tid < 256)
        atomicAdd(&out[b * F_DIM + tid], ored[tid] + ored[tid + 256]);
}

extern "C" void kernel_launch(void* const* d_in, const int* in_sizes, int n_in,
                              void* d_out, int out_size, void* d_ws, size_t ws_size,
                              hipStream_t stream) {
    const float* x = (const float*)d_in[0];     // (T,B,D) fp32
    const int* turns = (const int*)d_in[1];     // (B,) int32
    const float* W = (const float*)d_in[2];     // (D,F)
    const float* a1 = (const float*)d_in[3];    // (F,)
    const float* a2 = (const float*)d_in[4];    // (F,)
    float* out = (float*)d_out;                 // (B,F)
    float* ws = (float*)d_ws;

    g_uv<<<B_DIM, 256, 0, stream>>>(W, a1, a2, ws, out);
    g_pq<<<512, 512, 0, stream>>>(x, turns, ws);
    g_row<<<B_DIM * 12, 1024, 0, stream>>>(turns, ws);
    g_colzout<<<B_DIM * 4, 512, 0, stream>>>(x, turns, W, ws, out);
}

// Round 19
// 45.669 us; speedup vs baseline: 1.2350x; 1.0104x over previous
//
#include <hip/hip_runtime.h>
#include <math.h>

#define T_DIM 512
#define B_DIM 64
#define D_DIM 256
#define F_DIM 256
#define ALPHA 0.2f
#define L2E 1.44269504089f
#define NEGL -1.0e38f

// workspace layout (floats). Every slot consumed is written the same call.
#define P_OFF 0
#define Q_OFF (P_OFF + B_DIM * T_DIM)
#define FC_OFF (Q_OFF + B_DIM * T_DIM)    // float2 fc[3][B][T] = (f1_i, ci_i)

__device__ __forceinline__ float dot4(float4 a, float4 b) {
    return a.x * b.x + a.y * b.y + a.z * b.z + a.w * b.w;
}

// Wave64 sum via DPP butterfly (VALU-rate, no LDS pipe). Result in lane 63.
__device__ __forceinline__ float dpp_sum(float x) {
    union { float f; int i; } a, t;
    a.f = x;
    t.i = __builtin_amdgcn_update_dpp(0, a.i, 0x111, 0xf, 0xf, true); a.f += t.f; // row_shr:1
    t.i = __builtin_amdgcn_update_dpp(0, a.i, 0x112, 0xf, 0xf, true); a.f += t.f; // row_shr:2
    t.i = __builtin_amdgcn_update_dpp(0, a.i, 0x114, 0xf, 0xf, true); a.f += t.f; // row_shr:4
    t.i = __builtin_amdgcn_update_dpp(0, a.i, 0x118, 0xf, 0xf, true); a.f += t.f; // row_shr:8
    t.i = __builtin_amdgcn_update_dpp(0, a.i, 0x142, 0xf, 0xf, true); a.f += t.f; // row_bcast:15
    t.i = __builtin_amdgcn_update_dpp(0, a.i, 0x143, 0xf, 0xf, true); a.f += t.f; // row_bcast:31
    return a.f;  // lane 63 holds the wave sum
}

// ---------- Node 1: fused uv + pq. 512 blocks x 512 thr ----------
// u,v computed redundantly per block (W is L2-resident; 32 batched L2-hit rows
// per wave + DPP), then the proven clamp-trick pq body. Blocks 0-31 zero d_out.
__global__ __launch_bounds__(512) void g_pq(const float* __restrict__ x,
                                            const int* __restrict__ turns,
                                            const float* __restrict__ W,
                                            const float* __restrict__ a1,
                                            const float* __restrict__ a2,
                                            float* __restrict__ ws,
                                            float* __restrict__ out) {
    __shared__ float su[D_DIM], sv[D_DIM];
    int tid = threadIdx.x;
    int lane = tid & 63, wave = tid >> 6;
    if (blockIdx.x < 32) out[blockIdx.x * 512 + tid] = 0.f;  // zero d_out for Node 3

    // uv: wave handles d = wave*32 + k (k=0..31), 4 batches of 8 (all valid)
    {
        float4 a1v = ((const float4*)a1)[lane];
        float4 a2v = ((const float4*)a2)[lane];
        float4 wv[8];
#pragma unroll
        for (int c = 0; c < 4; ++c) {
#pragma unroll
            for (int k = 0; k < 8; ++k) {
                int d = wave * 32 + c * 8 + k;
                wv[k] = ((const float4*)(W + (size_t)d * F_DIM))[lane];
            }
#pragma unroll
            for (int k = 0; k < 8; ++k) {
                int d = wave * 32 + c * 8 + k;
                float p = dpp_sum(dot4(wv[k], a1v));
                float q = dpp_sum(dot4(wv[k], a2v));
                if (lane == 63) { su[d] = p; sv[d] = q; }
            }
        }
    }
    __syncthreads();

    int gw = blockIdx.x * 8 + wave;        // [0, 4096)
    int b = gw & 63;
    int tbase = gw >> 6;                   // [0, 64)
    int tn = turns[b];
    float4 uv = ((const float4*)su)[lane];
    float4 vv = ((const float4*)sv)[lane];
    float4 xv[8];
#pragma unroll
    for (int k = 0; k < 8; ++k) {
        int t = min(tbase + k * 64, tn);   // always valid address
        xv[k] = ((const float4*)x)[((size_t)t * B_DIM + b) * (D_DIM / 4) + lane];
    }
#pragma unroll
    for (int k = 0; k < 8; ++k) {
        int t = tbase + k * 64;
        if (t <= tn) {                     // wave-uniform
            float pp = dpp_sum(dot4(xv[k], uv));
            float qq = dpp_sum(dot4(xv[k], vv));
            if (lane == 63) {
                ws[P_OFF + b * T_DIM + t] = pp;
                ws[Q_OFF + b * T_DIM + t] = qq;
            }
        }
    }
}

// ---------- Node 2: balanced row pass, no atomics. 768 blocks (b,w,ic) x 1024 ----------
// Each block: full-j row sums for its 128 i's -> fc[(w-1)][b][i] = (f1_i, ci_i).
// Pads (i >= cnt) written as (0, 3e38) so downstream float4 loops need no tails.
// Octant guard (oct*64 < cnt) skips all-zero j-chunks wave-uniformly.
__global__ __launch_bounds__(1024) void g_row(const int* __restrict__ turns,
                                              float* __restrict__ ws) {
    int bi = blockIdx.x, tid = threadIdx.x;
    int b = bi / 12, rem = bi % 12;
    int w = (rem >> 2) + 1, ic = rem & 3;
    int tn = turns[b];
    int cnt = tn - w + 2;
    if (cnt > T_DIM) cnt = T_DIM;
    float2* FC = (float2*)(ws + FC_OFF) + ((w - 1) * B_DIM + b) * T_DIM;
    if (cnt <= 0) return;                  // block-uniform; fc never read for this w
    __shared__ float sp[T_DIM], sq[T_DIM], f2L[T_DIM];
    __shared__ float part[8][128];
    __shared__ float redm[8];
    if (tid < 128) ((float4*)sp)[tid] = ((const float4*)(ws + P_OFF + b * T_DIM))[tid];
    else if (tid < 256) ((float4*)sq)[tid - 128] = ((const float4*)(ws + Q_OFF + b * T_DIM))[tid - 128];
    __syncthreads();
    float scale = L2E / (float)w;
    int wave = tid >> 6, lane = tid & 63;
    if (tid < 512) {
        int j = tid;
        float v = NEGL;
        if (j < cnt) {                     // j+w-1 <= tn: valid
            float a = sq[j];
            if (w > 1) a += sq[j + 1];
            if (w > 2) a += sq[j + 2];
            v = a * scale;
        }
        f2L[j] = v;                        // padded NEGL beyond cnt
        float m = v;
        for (int off = 32; off > 0; off >>= 1) m = fmaxf(m, __shfl_down(m, off));
        if (lane == 0) redm[wave] = m;
    }
    __syncthreads();
    float M = redm[0];
#pragma unroll
    for (int k = 1; k < 8; ++k) M = fmaxf(M, redm[k]);

    int il = tid & 127, oct = tid >> 7;
    int i = ic * 128 + il;
    float r = 0.f;
    // oct*64 >= cnt -> whole j-chunk is NEGL-padded -> contribution exactly 0.
    if (i < cnt && oct * 64 < cnt) {
        float a = sp[i];
        if (w > 1) a += sp[i + 1];
        if (w > 2) a += sp[i + 2];
        float f1 = a * scale;
        float s0 = f1 + M;
        float mrow = fmaxf(s0, ALPHA * s0);   // analytic row max (lrelu monotone)
        const float4* fv = (const float4*)(f2L + oct * 64);
#pragma unroll 4
        for (int k = 0; k < 16; ++k) {        // 64 j's per octant, pad-safe
            float4 f = fv[k];
            float sa = f1 + f.x, sb = f1 + f.y, sc = f1 + f.z, sd = f1 + f.w;
            sa = fmaxf(sa, ALPHA * sa); sb = fmaxf(sb, ALPHA * sb);
            sc = fmaxf(sc, ALPHA * sc); sd = fmaxf(sd, ALPHA * sd);
            r += __builtin_amdgcn_exp2f(sa - mrow) + __builtin_amdgcn_exp2f(sb - mrow)
               + __builtin_amdgcn_exp2f(sc - mrow) + __builtin_amdgcn_exp2f(sd - mrow);
        }
    }
    part[oct][il] = r;
    __syncthreads();
    if (tid < 128) {
        int i2 = ic * 128 + tid;
        float2 pr = make_float2(0.f, 3.0e38f);   // pad: exp2(s - 3e38) = 0
        if (i2 < cnt) {
            float rt = part[0][tid];
#pragma unroll
            for (int k = 1; k < 8; ++k) rt += part[k][tid];
            float a = sp[i2];
            if (w > 1) a += sp[i2 + 1];
            if (w > 2) a += sp[i2 + 2];
            float f1 = a * scale;
            float s0 = f1 + M;
            float mrow = fmaxf(s0, ALPHA * s0);
            pr = make_float2(f1, mrow + __builtin_amdgcn_logf(rt));   // log2 domain
        }
        FC[i2] = pr;
    }
}

// ---------- Node 3: col pass + Z + GEMV -> atomicAdd out. 256 blocks x 512 ----------
// Phase I i-quarter wave-uniform (iq = tid>>7) and skippable.
__global__ __launch_bounds__(512) void g_colzout(const float* __restrict__ x,
                                                 const int* __restrict__ turns,
                                                 const float* __restrict__ W,
                                                 const float* __restrict__ ws,
                                                 float* __restrict__ out) {
    int b = blockIdx.x >> 2, chunk = blockIdx.x & 3;
    int tn = turns[b];
    int t0 = chunk * 128;
    if (t0 > tn) return;                   // C=0 there; out zeroed in Node 1
    int tid = threadIdx.x;
    __shared__ float sq[T_DIM];
    __shared__ float4 fcs4[3][T_DIM / 2];  // fc pairs, float4 = 2 (f1,ci) pairs
    __shared__ float Gs[3][132];
    __shared__ float partq[128][4];
    __shared__ float part2[2][128];
    __shared__ float Cs[128];
    __shared__ float4 zp[512];
    __shared__ float Zs[D_DIM];
    __shared__ float ored[512];

    if (tid < 128) ((float4*)sq)[tid] = ((const float4*)(ws + Q_OFF + b * T_DIM))[tid];
    for (int k = tid; k < 3 * 256; k += 512) {
        int wi = k >> 8, kk = k & 255;
        fcs4[wi][kk] = ((const float4*)(ws + FC_OFF))[(wi * B_DIM + b) * 256 + kk];
    }
    __syncthreads();

    for (int w = 1; w <= 3; ++w) {
        int cw = tn - w + 2;
        if (cw > T_DIM) cw = T_DIM;
        bool act = cw > 0;                 // block-uniform
        float scale = L2E / (float)w;
        if (act) {
            // phase I: j = t0 + (tid&127), i-quarter iq = tid>>7 (wave-uniform).
            {
                int jj = tid & 127, iq = tid >> 7;
                int j = t0 + jj;
                float acc = 0.f;
                if (j < cw && iq * 128 < cw) {
                    float a = sq[j];
                    if (w > 1) a += sq[j + 1];
                    if (w > 2) a += sq[j + 2];
                    float f2j = a * scale;
                    const float4* fv = fcs4[w - 1] + iq * 64;
                    for (int k = 0; k < 64; ++k) {       // pad-safe
                        float4 f = fv[k];
                        float sa = f.x + f2j, sb = f.z + f2j;
                        sa = fmaxf(sa, ALPHA * sa); sb = fmaxf(sb, ALPHA * sb);
                        acc += __builtin_amdgcn_exp2f(sa - f.y)
                             + __builtin_amdgcn_exp2f(sb - f.w);
                    }
                }
                partq[jj][iq] = acc;
            }
            // phase II: j = t0-2, t0-1; 128-way i-split (2 float4 = 4 i each)
            if (tid < 256) {
                int e = tid >> 7, q2 = tid & 127;
                int j2 = t0 - 2 + e;
                float acc = 0.f;
                if (j2 >= 0 && j2 < cw) {
                    float a = sq[j2];
                    if (w > 1) a += sq[j2 + 1];
                    if (w > 2) a += sq[j2 + 2];
                    float f2j = a * scale;
                    const float4* fv = fcs4[w - 1] + q2 * 2;
#pragma unroll
                    for (int k = 0; k < 2; ++k) {
                        float4 f = fv[k];
                        float sa = f.x + f2j, sb = f.z + f2j;
                        sa = fmaxf(sa, ALPHA * sa); sb = fmaxf(sb, ALPHA * sb);
                        acc += __builtin_amdgcn_exp2f(sa - f.y)
                             + __builtin_amdgcn_exp2f(sb - f.w);
                    }
                }
                part2[e][q2] = acc;
            }
        }
        __syncthreads();
        if (act) {
            float invc = 1.0f / (float)cw;
            if (tid < 128) {
                int j = t0 + tid;
                float s = partq[tid][0] + partq[tid][1] + partq[tid][2] + partq[tid][3];
                Gs[w - 1][2 + tid] = (j < cw) ? s * invc : 0.f;
            } else if (tid < 130) {
                int e = tid - 128;
                int j2 = t0 - 2 + e;
                float s = 0.f;
                for (int k = 0; k < 128; ++k) s += part2[e][k];
                Gs[w - 1][e] = (j2 >= 0 && j2 < cw) ? s * invc : 0.f;
            }
        } else if (tid < 132) {
            Gs[w - 1][tid] = 0.f;
        }
        __syncthreads();
    }

    // C[t] with vws folded
    if (tid < 128) {
        float g1 = Gs[0][2 + tid];
        float g2 = Gs[1][2 + tid] + Gs[1][1 + tid];
        float g3 = Gs[2][2 + tid] + Gs[2][1 + tid] + Gs[2][tid];
        float vws = 1.f + (tn >= 1 ? 1.f : 0.f) + (tn >= 2 ? 1.f : 0.f);
        Cs[tid] = (g1 + 0.5f * g2 + (1.0f / 3.0f) * g3) / vws;
    }
    __syncthreads();

    // Z accumulate over this t-chunk (proven body)
    int wave = tid >> 6, lane = tid & 63;
    float4 z = make_float4(0.f, 0.f, 0.f, 0.f);
    {
        size_t base = ((size_t)(t0 + wave * 16) * B_DIM + b) * (D_DIM / 4) + lane;
#pragma unroll 8
        for (int tt = 0; tt < 16; ++tt) {
            float c = Cs[wave * 16 + tt];
            float4 xv = ((const float4*)x)[base + (size_t)tt * (B_DIM * D_DIM / 4)];
            z.x += c * xv.x; z.y += c * xv.y; z.z += c * xv.z; z.w += c * xv.w;
        }
    }
    zp[tid] = z;
    __syncthreads();
    if (tid < 64) {
        float4 a = zp[tid];
#pragma unroll
        for (int k = 1; k < 8; ++k) {
            float4 bb = zp[k * 64 + tid];
            a.x += bb.x; a.y += bb.y; a.z += bb.z; a.w += bb.w;
        }
        ((float4*)Zs)[tid] = a;
    }
    __syncthreads();
    int f = tid & 255, dh = tid >> 8;
    float acc = 0.f;
#pragma unroll 8
    for (int dd = dh * 128; dd < dh * 128 + 128; ++dd)
        acc += Zs[dd] * W[(size_t)dd * F_DIM + f];
    ored[tid] = acc;
    __syncthreads();
    if (tid < 256)
        atomicAdd(&out[b * F_DIM + tid], ored[tid] + ored[tid + 256]);
}

extern "C" void kernel_launch(void* const* d_in, const int* in_sizes, int n_in,
                              void* d_out, int out_size, void* d_ws, size_t ws_size,
                              hipStream_t stream) {
    const float* x = (const float*)d_in[0];     // (T,B,D) fp32
    const int* turns = (const int*)d_in[1];     // (B,) int32
    const float* W = (const float*)d_in[2];     // (D,F)
    const float* a1 = (const float*)d_in[3];    // (F,)
    const float* a2 = (const float*)d_in[4];    // (F,)
    float* out = (float*)d_out;                 // (B,F)
    float* ws = (float*)d_ws;

    g_pq<<<512, 512, 0, stream>>>(x, turns, W, a1, a2, ws, out);
    g_row<<<B_DIM * 12, 1024, 0, stream>>>(turns, ws);
    g_colzout<<<B_DIM * 4, 512, 0, stream>>>(x, turns, W, ws, out);
}